// Round 3
// baseline (151.856 us; speedup 1.0000x reference)
//
#include <hip/hip_runtime.h>
#include <math.h>

#define STEPS 3
#define BS 8
#define NCH 256
#define H 64
#define W 64
#define UP 8
#define OH (H*UP)
#define OW (W*UP)
#define G 32              // channel groups (atomic partial sums)
#define CPG (NCH/G)       // 8 channels per group
#define WREC 32           // floats per packed weight record (27 taps + w_head + pad)
#define DMAP_FLOATS (STEPS*BS*H*W)   // 98304
#define PREP_N (STEPS*28*BS*NCH)     // 172032

// ---- prep: zero dmap accumulator + transpose prototypes into contiguous
// per-(b,c) records holding all 3 steps: wt[((b*NCH+c)*STEPS + i)*WREC + j]
__global__ __launch_bounds__(256) void loca_prep(
    const float* __restrict__ ap, const float* __restrict__ w_head,
    float* __restrict__ wt, float* __restrict__ dmap)
{
    int t = blockIdx.x * 256 + threadIdx.x;
    if (t < DMAP_FLOATS) dmap[t] = 0.f;
    if (t >= PREP_N) return;
    int c = t & (NCH - 1);
    int r = t >> 8;
    int b = r & (BS - 1);
    r >>= 3;
    int j = r % 28;
    int i = r / 28;
    float v = (j < 27) ? ap[(((size_t)i * 27 + j) * BS + b) * NCH + c] : w_head[c];
    wt[(((size_t)b * NCH + c) * STEPS + i) * WREC + j] = v;
}

// ---- fused dmap: per channel, load rows + shfl ONCE, apply all 3 steps'
// weights. Barrier-free, LDS-free; channel groups atomicAdd into dmap.
__global__ __launch_bounds__(256) void loca_dmap(
    const float* __restrict__ f_e,   // [BS, NCH, H, W]
    const float* __restrict__ wt,    // [(b*NCH+c)*STEPS + i][WREC]
    float* __restrict__ dmap)        // [STEPS*BS, H, W] accumulator
{
    const int lane = threadIdx.x & 63;
    const int wid  = threadIdx.x >> 6;
    const int g    = blockIdx.z;                 // channel group 0..31
    const int b    = blockIdx.y;
    const int row  = blockIdx.x * 16 + wid * 4 + (lane >> 4);
    const int xg   = lane & 15;
    const int c0   = g * CPG;

    const float m_m1 = (row > 0)     ? 1.f : 0.f;
    const float m_p1 = (row < H - 1) ? 1.f : 0.f;
    const int r_m1 = row > 0     ? row - 1 : 0;
    const int r_p1 = row < H - 1 ? row + 1 : H - 1;

    const float* fb = f_e + ((size_t)b * NCH + c0) * (H * W);
    const float* wb = wt  + ((size_t)b * NCH + c0) * (STEPS * WREC);

    float acc[STEPS][4] = {};

    // software pipeline: preload channel 0
    float4 nm = ((const float4*)(fb + r_m1 * W))[xg];
    float4 n0 = ((const float4*)(fb + row  * W))[xg];
    float4 np = ((const float4*)(fb + r_p1 * W))[xg];

    for (int cc = 0; cc < CPG; ++cc) {
        float4 vm = nm, v0 = n0, vp = np;
        if (cc + 1 < CPG) {
            const float* fc = fb + (cc + 1) * (H * W);
            nm = ((const float4*)(fc + r_m1 * W))[xg];
            n0 = ((const float4*)(fc + row  * W))[xg];
            np = ((const float4*)(fc + r_p1 * W))[xg];
        }
        vm.x *= m_m1; vm.y *= m_m1; vm.z *= m_m1; vm.w *= m_m1;
        vp.x *= m_p1; vp.y *= m_p1; vp.z *= m_p1; vp.w *= m_p1;

        // horizontal neighbors; 16-lane segment edges == image x-edges
        float Lm = __shfl_up(vm.w, 1);
        float L0 = __shfl_up(v0.w, 1);
        float Lp = __shfl_up(vp.w, 1);
        float Rm = __shfl_down(vm.x, 1);
        float R0 = __shfl_down(v0.x, 1);
        float Rp = __shfl_down(vp.x, 1);
        if (xg == 0)  { Lm = 0.f; L0 = 0.f; Lp = 0.f; }
        if (xg == 15) { Rm = 0.f; R0 = 0.f; Rp = 0.f; }

        float am[6]  = {Lm, vm.x, vm.y, vm.z, vm.w, Rm};
        float a0[6]  = {L0, v0.x, v0.y, v0.z, v0.w, R0};
        float apv[6] = {Lp, vp.x, vp.y, vp.z, vp.w, Rp};

        const float* wc = wb + cc * (STEPS * WREC);  // wave-uniform -> s_load

        #pragma unroll
        for (int i = 0; i < STEPS; ++i) {
            const float* w = wc + i * WREC;
            float wh = w[27];
            #pragma unroll
            for (int k = 0; k < 4; ++k) {
                float r_[3];
                #pragma unroll
                for (int o = 0; o < 3; ++o) {
                    const float* q = w + o * 9;
                    float t = am[k] * q[0];
                    t = fmaf(am[k+1],  q[1], t);
                    t = fmaf(am[k+2],  q[2], t);
                    t = fmaf(a0[k],    q[3], t);
                    t = fmaf(a0[k+1],  q[4], t);
                    t = fmaf(a0[k+2],  q[5], t);
                    t = fmaf(apv[k],   q[6], t);
                    t = fmaf(apv[k+1], q[7], t);
                    t = fmaf(apv[k+2], q[8], t);
                    r_[o] = t;
                }
                float mx = fmaxf(r_[0], fmaxf(r_[1], r_[2]));
                float e0 = __expf(r_[0] - mx);
                float e1 = __expf(r_[1] - mx);
                float e2 = __expf(r_[2] - mx);
                float num = fmaf(e0, r_[0], fmaf(e1, r_[1], e2 * r_[2]));
                float den = e0 + e1 + e2;
#if __has_builtin(__builtin_amdgcn_rcpf)
                float red = num * __builtin_amdgcn_rcpf(den);
#else
                float red = num / den;
#endif
                acc[i][k] = fmaf(wh, red, acc[i][k]);
            }
        }
    }

    #pragma unroll
    for (int i = 0; i < STEPS; ++i) {
        float* dp = dmap + (size_t)(i * BS + b) * (H * W) + row * W + xg * 4;
        #pragma unroll
        for (int k = 0; k < 4; ++k) {
#if defined(__gfx90a__) || defined(__gfx940__) || defined(__gfx941__) || defined(__gfx942__) || defined(__gfx950__)
            unsafeAtomicAdd(dp + k, acc[i][k]);
#else
            atomicAdd(dp + k, acc[i][k]);
#endif
        }
    }
}

// ---- bilinear 8x upsample with fused bias+relu ----------------------------
__global__ __launch_bounds__(256) void loca_upsample(
    const float* __restrict__ dmap, const float* __restrict__ b_head,
    float* __restrict__ out)
{
    const int idx  = blockIdx.x * 256 + threadIdx.x;   // one float4 group
    const int gx   = idx & (OW / 4 - 1);               // 0..127
    const int rest = idx >> 7;
    const int Y    = rest & (OH - 1);                  // 0..511
    const int ib   = rest >> 9;                        // 0..23
    const float bias = b_head[0];

    const float* d = dmap + (size_t)ib * H * W;

    float yin = (Y + 0.5f) * 0.125f - 0.5f;
    float fy0 = floorf(yin);
    int   iy  = (int)fy0;
    float fy  = yin - fy0;
    int y0c = min(max(iy, 0), H - 1);
    int y1c = min(max(iy + 1, 0), H - 1);
    const float* row0 = d + y0c * W;
    const float* row1 = d + y1c * W;

    float4 o;
    float* op = &o.x;
    #pragma unroll
    for (int j = 0; j < 4; ++j) {
        int X = gx * 4 + j;
        float xin = (X + 0.5f) * 0.125f - 0.5f;
        float fx0 = floorf(xin);
        int   ix  = (int)fx0;
        float fx  = xin - fx0;
        int x0c = min(max(ix, 0), W - 1);
        int x1c = min(max(ix + 1, 0), W - 1);
        float a00 = fmaxf(row0[x0c] + bias, 0.f);
        float a01 = fmaxf(row0[x1c] + bias, 0.f);
        float a10 = fmaxf(row1[x0c] + bias, 0.f);
        float a11 = fmaxf(row1[x1c] + bias, 0.f);
        float v0 = a00 + fx * (a01 - a00);
        float v1 = a10 + fx * (a11 - a10);
        op[j] = v0 + fy * (v1 - v0);
    }
    ((float4*)out)[idx] = o;
}

extern "C" void kernel_launch(void* const* d_in, const int* in_sizes, int n_in,
                              void* d_out, int out_size, void* d_ws, size_t ws_size,
                              hipStream_t stream) {
    const float* f_e    = (const float*)d_in[0];
    const float* ap     = (const float*)d_in[1];
    const float* w_head = (const float*)d_in[2];
    const float* b_head = (const float*)d_in[3];
    float* out  = (float*)d_out;
    float* dmap = (float*)d_ws;                      // 98304 floats
    float* wt   = dmap + DMAP_FLOATS;                // 196608 floats

    loca_prep<<<(PREP_N + 255) / 256, 256, 0, stream>>>(ap, w_head, wt, dmap);

    dim3 g1(H / 16, BS, G);   // 4 x 8 x 32 = 1024 blocks
    loca_dmap<<<g1, 256, 0, stream>>>(f_e, wt, dmap);

    const int groups = STEPS * BS * OH * OW / 4;     // 1,572,864
    loca_upsample<<<groups / 256, 256, 0, stream>>>(dmap, b_head, out);
}

// Round 4
// 120.002 us; speedup vs baseline: 1.2654x; 1.2654x over previous
//
#include <hip/hip_runtime.h>
#include <math.h>

#define STEPS 3
#define BS 8
#define NCH 256
#define H 64
#define W 64
#define UP 8
#define OH (H*UP)
#define OW (W*UP)
#define GB 16              // channel groups (one partial buffer each)
#define CPB (NCH/GB)       // 16 channels per block
#define CPW (CPB/4)        // 4 channels per wave
#define WREC 32            // floats per packed weight record (27 taps + w_head + pad)
#define DMAP_FLOATS (STEPS*BS*H*W)   // 98304
#define PREP_N (STEPS*28*BS*NCH)     // 172032

// ---- prep: transpose prototypes into contiguous per-(b,c) records ---------
// wt[((b*NCH+c)*STEPS + i)*WREC + j] = j<27 ? ap[((i*27+j)*BS+b)*NCH+c] : w_head[c]
__global__ __launch_bounds__(256) void loca_prep(
    const float* __restrict__ ap, const float* __restrict__ w_head,
    float* __restrict__ wt)
{
    int t = blockIdx.x * 256 + threadIdx.x;
    if (t >= PREP_N) return;
    int c = t & (NCH - 1);
    int r = t >> 8;
    int b = r & (BS - 1);
    r >>= 3;
    int j = r % 28;
    int i = r / 28;
    float v = (j < 27) ? ap[(((size_t)i * 27 + j) * BS + b) * NCH + c] : w_head[c];
    wt[(((size_t)b * NCH + c) * STEPS + i) * WREC + j] = v;
}

// ---- fused dmap: 4 waves/block share 4 rows, split 16 channels 4-way.
// Weights broadcast from LDS; LDS tree-reduce across waves; plain float4
// partial stores (NO global atomics).
__global__ __launch_bounds__(256) void loca_dmap(
    const float* __restrict__ f_e,    // [BS, NCH, H, W]
    const float* __restrict__ wt,     // [(b*NCH+c)*STEPS + i][WREC]
    float* __restrict__ partial)      // [GB][STEPS][BS][H][W]
{
    __shared__ float wlds[CPB * STEPS * WREC];   // 1536 floats = 6 KB
    __shared__ float red[4][STEPS][256];         // 12 KB

    const int tid  = threadIdx.x;
    const int lane = tid & 63;
    const int wv   = tid >> 6;                   // wave 0..3
    const int rb   = blockIdx.x;                 // rowband 0..15
    const int b    = blockIdx.y;
    const int g    = blockIdx.z;                 // channel group 0..15
    const int row  = rb * 4 + (lane >> 4);
    const int xg   = lane & 15;
    const int C0   = g * CPB;

    // Stage this block's weights: 16 ch x 3 steps x 32 floats, contiguous.
    {
        const float4* src = (const float4*)(wt + ((size_t)b * NCH + C0) * (STEPS * WREC));
        float4* dst = (float4*)wlds;
        dst[tid] = src[tid];
        if (tid < CPB * STEPS * WREC / 4 - 256)
            dst[256 + tid] = src[256 + tid];
    }
    __syncthreads();

    const float m_m1 = (row > 0)     ? 1.f : 0.f;
    const float m_p1 = (row < H - 1) ? 1.f : 0.f;
    const int r_m1 = row > 0     ? row - 1 : 0;
    const int r_p1 = row < H - 1 ? row + 1 : H - 1;

    const int cw = C0 + wv * CPW;                // this wave's first channel
    const float* fb = f_e + ((size_t)b * NCH + cw) * (H * W);

    float acc[STEPS][4] = {};

    // software pipeline: preload channel 0
    float4 nm = ((const float4*)(fb + r_m1 * W))[xg];
    float4 n0 = ((const float4*)(fb + row  * W))[xg];
    float4 np = ((const float4*)(fb + r_p1 * W))[xg];

    for (int cc = 0; cc < CPW; ++cc) {
        float4 vm = nm, v0 = n0, vp = np;
        if (cc + 1 < CPW) {
            const float* fc = fb + (cc + 1) * (H * W);
            nm = ((const float4*)(fc + r_m1 * W))[xg];
            n0 = ((const float4*)(fc + row  * W))[xg];
            np = ((const float4*)(fc + r_p1 * W))[xg];
        }
        vm.x *= m_m1; vm.y *= m_m1; vm.z *= m_m1; vm.w *= m_m1;
        vp.x *= m_p1; vp.y *= m_p1; vp.z *= m_p1; vp.w *= m_p1;

        // horizontal neighbors; 16-lane segment edges == image x-edges
        float Lm = __shfl_up(vm.w, 1);
        float L0 = __shfl_up(v0.w, 1);
        float Lp = __shfl_up(vp.w, 1);
        float Rm = __shfl_down(vm.x, 1);
        float R0 = __shfl_down(v0.x, 1);
        float Rp = __shfl_down(vp.x, 1);
        if (xg == 0)  { Lm = 0.f; L0 = 0.f; Lp = 0.f; }
        if (xg == 15) { Rm = 0.f; R0 = 0.f; Rp = 0.f; }

        float am[6]  = {Lm, vm.x, vm.y, vm.z, vm.w, Rm};
        float a0[6]  = {L0, v0.x, v0.y, v0.z, v0.w, R0};
        float apv[6] = {Lp, vp.x, vp.y, vp.z, vp.w, Rp};

        const int lc = wv * CPW + cc;            // local channel 0..15

        #pragma unroll
        for (int i = 0; i < STEPS; ++i) {
            // 7 x ds_read_b128 broadcast of this (channel, step)'s 28 floats
            union { float4 v4[7]; float f[28]; } qq;
            const float4* wp4 = (const float4*)(wlds + ((size_t)lc * STEPS + i) * WREC);
            #pragma unroll
            for (int q = 0; q < 7; ++q) qq.v4[q] = wp4[q];
            const float wh = qq.f[27];

            #pragma unroll
            for (int k = 0; k < 4; ++k) {
                float r_[3];
                #pragma unroll
                for (int o = 0; o < 3; ++o) {
                    float t = am[k] * qq.f[o * 9 + 0];
                    t = fmaf(am[k+1],  qq.f[o * 9 + 1], t);
                    t = fmaf(am[k+2],  qq.f[o * 9 + 2], t);
                    t = fmaf(a0[k],    qq.f[o * 9 + 3], t);
                    t = fmaf(a0[k+1],  qq.f[o * 9 + 4], t);
                    t = fmaf(a0[k+2],  qq.f[o * 9 + 5], t);
                    t = fmaf(apv[k],   qq.f[o * 9 + 6], t);
                    t = fmaf(apv[k+1], qq.f[o * 9 + 7], t);
                    t = fmaf(apv[k+2], qq.f[o * 9 + 8], t);
                    r_[o] = t;
                }
                float mx = fmaxf(r_[0], fmaxf(r_[1], r_[2]));
                float e0 = __expf(r_[0] - mx);
                float e1 = __expf(r_[1] - mx);
                float e2 = __expf(r_[2] - mx);
                float num = fmaf(e0, r_[0], fmaf(e1, r_[1], e2 * r_[2]));
                float den = e0 + e1 + e2;
#if __has_builtin(__builtin_amdgcn_rcpf)
                float redv = num * __builtin_amdgcn_rcpf(den);
#else
                float redv = num / den;
#endif
                acc[i][k] = fmaf(wh, redv, acc[i][k]);
            }
        }
    }

    // cross-wave reduce in LDS, then one plain float4 store per (thread, step)
    const int px = (lane >> 4) * 64 + xg * 4;    // 0..255 within the rowband
    #pragma unroll
    for (int i = 0; i < STEPS; ++i) {
        float4 a; a.x = acc[i][0]; a.y = acc[i][1]; a.z = acc[i][2]; a.w = acc[i][3];
        *(float4*)&red[wv][i][px] = a;
    }
    __syncthreads();
    #pragma unroll
    for (int i = 0; i < STEPS; ++i) {
        float4 s0 = *(const float4*)&red[0][i][px];
        float4 s1 = *(const float4*)&red[1][i][px];
        float4 s2 = *(const float4*)&red[2][i][px];
        float4 s3 = *(const float4*)&red[3][i][px];
        float4 s;
        s.x = (s0.x + s1.x) + (s2.x + s3.x);
        s.y = (s0.y + s1.y) + (s2.y + s3.y);
        s.z = (s0.z + s1.z) + (s2.z + s3.z);
        s.w = (s0.w + s1.w) + (s2.w + s3.w);
        *(float4*)&partial[(size_t)g * DMAP_FLOATS + ((size_t)(i * BS + b)) * (H * W)
                           + row * W + xg * 4] = s;
    }
}

// ---- reduce GB partials -> dmap, fused bias + relu ------------------------
__global__ __launch_bounds__(256) void loca_reduce(
    const float* __restrict__ partial, const float* __restrict__ b_head,
    float* __restrict__ dmap)
{
    const int t = blockIdx.x * 256 + threadIdx.x;   // 0..24575 (float4 units)
    const float4* p = (const float4*)partial;
    float4 s = p[t];
    #pragma unroll
    for (int g = 1; g < GB; ++g) {
        float4 q = p[(size_t)g * (DMAP_FLOATS / 4) + t];
        s.x += q.x; s.y += q.y; s.z += q.z; s.w += q.w;
    }
    const float bias = b_head[0];
    s.x = fmaxf(s.x + bias, 0.f);
    s.y = fmaxf(s.y + bias, 0.f);
    s.z = fmaxf(s.z + bias, 0.f);
    s.w = fmaxf(s.w + bias, 0.f);
    ((float4*)dmap)[t] = s;
}

// ---- bilinear 8x upsample (bias/relu already applied) ---------------------
__global__ __launch_bounds__(256) void loca_upsample(
    const float* __restrict__ dmap, float* __restrict__ out)
{
    const int idx  = blockIdx.x * 256 + threadIdx.x;   // one float4 group
    const int gx   = idx & (OW / 4 - 1);               // 0..127
    const int rest = idx >> 7;
    const int Y    = rest & (OH - 1);                  // 0..511
    const int ib   = rest >> 9;                        // 0..23

    const float* d = dmap + (size_t)ib * H * W;

    float yin = (Y + 0.5f) * 0.125f - 0.5f;
    float fy0 = floorf(yin);
    int   iy  = (int)fy0;
    float fy  = yin - fy0;
    int y0c = min(max(iy, 0), H - 1);
    int y1c = min(max(iy + 1, 0), H - 1);
    const float* row0 = d + y0c * W;
    const float* row1 = d + y1c * W;

    float4 o;
    float* op = &o.x;
    #pragma unroll
    for (int j = 0; j < 4; ++j) {
        int X = gx * 4 + j;
        float xin = (X + 0.5f) * 0.125f - 0.5f;
        float fx0 = floorf(xin);
        int   ix  = (int)fx0;
        float fx  = xin - fx0;
        int x0c = min(max(ix, 0), W - 1);
        int x1c = min(max(ix + 1, 0), W - 1);
        float a00 = row0[x0c], a01 = row0[x1c];
        float a10 = row1[x0c], a11 = row1[x1c];
        float v0 = a00 + fx * (a01 - a00);
        float v1 = a10 + fx * (a11 - a10);
        op[j] = v0 + fy * (v1 - v0);
    }
    ((float4*)out)[idx] = o;
}

extern "C" void kernel_launch(void* const* d_in, const int* in_sizes, int n_in,
                              void* d_out, int out_size, void* d_ws, size_t ws_size,
                              hipStream_t stream) {
    const float* f_e    = (const float*)d_in[0];
    const float* ap     = (const float*)d_in[1];
    const float* w_head = (const float*)d_in[2];
    const float* b_head = (const float*)d_in[3];
    float* out  = (float*)d_out;
    float* dmap = (float*)d_ws;                      // 98304 floats
    float* wt   = dmap + DMAP_FLOATS;                // 196608 floats
    // partial buffers live in d_out's head (6.3 MB of 25 MB); consumed by
    // loca_reduce before loca_upsample overwrites all of d_out.
    float* partial = out;

    loca_prep<<<(PREP_N + 255) / 256, 256, 0, stream>>>(ap, w_head, wt);

    dim3 g1(16, BS, GB);   // 16 rowbands x 8 b x 16 groups = 2048 blocks
    loca_dmap<<<g1, 256, 0, stream>>>(f_e, wt, partial);

    loca_reduce<<<DMAP_FLOATS / 4 / 256, 256, 0, stream>>>(partial, b_head, dmap);

    const int groups = STEPS * BS * OH * OW / 4;     // 1,572,864
    loca_upsample<<<groups / 256, 256, 0, stream>>>(dmap, out);
}